// Round 4
// baseline (257.013 us; speedup 1.0000x reference)
//
#include <hip/hip_runtime.h>

#define H 128

typedef __attribute__((ext_vector_type(8))) short s16x8;
typedef __attribute__((ext_vector_type(4))) float f32x4;

__device__ __forceinline__ float bf2f(unsigned short u){
  unsigned x = ((unsigned)u) << 16;
  return __builtin_bit_cast(float, x);
}
__device__ __forceinline__ unsigned short f2bf(float f){
  unsigned u = __builtin_bit_cast(unsigned, f);
  u += 0x7fff + ((u >> 16) & 1);
  return (unsigned short)(u >> 16);
}

// ---- weight prep ----
// Wbig' permuted: row' = q*4+g, g=0:r 1:z 2:(i_n+h_n) 3:h_n(zero x|c block). K=[x|c|h].
// biasb'[q*4+g]: g<3: b_ih[g*128+q]+b_hh[g*128+q]; g=3: b_hh[256+q].
__global__ void prep_kernel(const float* W_msg, const float* W_ih, const float* W_hh,
                            const float* b_ih, const float* b_hh,
                            unsigned short* Wmsgb, unsigned short* Wbig, float* biasb){
  int i = blockIdx.x*256 + threadIdx.x;
  const int NW = 512*384;
  if(i < NW){
    int r = i / 384, k = i % 384;
    int q = r >> 2, g = r & 3;
    float v;
    if(g < 3){
      int orow = g*128 + q;
      v = (k < 256) ? W_ih[orow*256 + k] : W_hh[orow*128 + (k-256)];
    } else {
      v = (k < 256) ? 0.f : W_hh[(256 + q)*128 + (k-256)];
    }
    Wbig[i] = f2bf(v);
  } else if(i < NW + 128*256){
    int j = i - NW;
    Wmsgb[j] = f2bf(W_msg[j]);
  } else if(i < NW + 128*256 + 512){
    int r = i - NW - 128*256;
    int q = r >> 2, g = r & 3;
    biasb[r] = (g < 3) ? (b_ih[g*128+q] + b_hh[g*128+q]) : b_hh[256+q];
  }
}

// ---- convert x,h f32 -> bf16 interleaved xh[N][256] (x: cols 0..127, h: cols 128..255) ----
__global__ void convert_kernel(const float* x, const float* h,
                               unsigned short* xh, int nv){
  int i = blockIdx.x*256 + threadIdx.x;
  const float* sp; int j, add;
  if(i < nv){ sp = x; j = i; add = 0; }
  else if(i < 2*nv){ sp = h; j = i - nv; add = 128; }
  else return;
  float4 v = ((const float4*)sp)[j];
  ushort4 o; o.x=f2bf(v.x); o.y=f2bf(v.y); o.z=f2bf(v.z); o.w=f2bf(v.w);
  int node = j >> 5, col = (j & 31)*4;
  *(ushort4*)(xh + (long)node*256 + add + col) = o;
}

// ---- CSR build ----
__global__ void hist_kernel(const int* dst, int* deg, int E){
  int e = blockIdx.x*256 + threadIdx.x;
  if(e < E) atomicAdd(&deg[dst[e]], 1);
}

__global__ void scanA_kernel(const int* deg, int* rs, int* bsum, int N){
  __shared__ int buf[256];
  int b = blockIdx.x, t = threadIdx.x;
  int base = b*2048 + t*8;
  int v[8]; int s = 0;
  #pragma unroll
  for(int j=0;j<8;++j){ int idx = base+j; v[j] = (idx<N)?deg[idx]:0; s += v[j]; }
  buf[t] = s; __syncthreads();
  #pragma unroll
  for(int off=1; off<256; off<<=1){
    int u = (t>=off)?buf[t-off]:0;
    __syncthreads();
    buf[t] += u;
    __syncthreads();
  }
  int run = buf[t] - s;
  #pragma unroll
  for(int j=0;j<8;++j){ int idx = base+j; if(idx<N) rs[idx] = run; run += v[j]; }
  if(t == 255) bsum[b] = buf[255];
}

__global__ void scanB_kernel(int* bsum, int* rsN, int nb){
  __shared__ int buf[64];
  int t = threadIdx.x;
  int v = (t < nb) ? bsum[t] : 0;
  buf[t] = v; __syncthreads();
  #pragma unroll
  for(int off=1; off<64; off<<=1){
    int u = (t>=off)?buf[t-off]:0;
    __syncthreads();
    buf[t] += u;
    __syncthreads();
  }
  if(t < nb) bsum[t] = buf[t] - v;
  if(t == 63) *rsN = buf[63];
}

__global__ void scanC_kernel(int* rs, int* rc, const int* bsum, int N){
  int i = blockIdx.x*256 + threadIdx.x;
  if(i < N){ int v = rs[i] + bsum[i >> 11]; rs[i] = v; rc[i] = v; }
}

__global__ void fill_kernel(const int* src, const int* dst, int* rc, int* ss, int E){
  int e = blockIdx.x*256 + threadIdx.x;
  if(e < E){ int p = atomicAdd(&rc[dst[e]], 1); ss[p] = src[e]; }
}

// ---- aggregation: one wave per node; 2 edges/iter (half-wave each, 16B/lane), unroll x2 ----
__global__ void agg_kernel(const unsigned short* xh, const int* rs, const int* ss,
                           unsigned short* Sb, int N){
  int wv = threadIdx.x >> 6, lane = threadIdx.x & 63;
  int node = blockIdx.x*4 + wv;
  if(node >= N) return;
  int e0 = rs[node], e1 = rs[node+1];
  int half = lane >> 5;
  int co = (lane & 31)*8;
  float a[8] = {0.f,0.f,0.f,0.f,0.f,0.f,0.f,0.f};
  int cnt = e1 - e0;
  int pairs = cnt >> 1;
  int i = 0;
  for(; i+1 < pairs; i += 2){
    int ea = e0 + 2*i + half;
    int eb = ea + 2;
    int sa = ss[ea], sb = ss[eb];
    s16x8 va = *(const s16x8*)(xh + (long)sa*256 + co);
    s16x8 vb = *(const s16x8*)(xh + (long)sb*256 + co);
    #pragma unroll
    for(int j=0;j<8;++j) a[j] += bf2f((unsigned short)va[j]);
    #pragma unroll
    for(int j=0;j<8;++j) a[j] += bf2f((unsigned short)vb[j]);
  }
  for(; i < pairs; ++i){
    int ea = e0 + 2*i + half;
    int sa = ss[ea];
    s16x8 va = *(const s16x8*)(xh + (long)sa*256 + co);
    #pragma unroll
    for(int j=0;j<8;++j) a[j] += bf2f((unsigned short)va[j]);
  }
  if((cnt & 1) && half == 0){
    int sa = ss[e1-1];
    s16x8 va = *(const s16x8*)(xh + (long)sa*256 + co);
    #pragma unroll
    for(int j=0;j<8;++j) a[j] += bf2f((unsigned short)va[j]);
  }
  #pragma unroll
  for(int j=0;j<8;++j) a[j] += __shfl_xor(a[j], 32, 64);
  if(half == 0){
    float inv = (cnt > 0) ? 1.0f/(float)cnt : 0.f;
    unsigned short o[8];
    #pragma unroll
    for(int j=0;j<8;++j) o[j] = f2bf(a[j]*inv);
    *(s16x8*)(Sb + (long)node*256 + co) = *(const s16x8*)o;
  }
}

// ---- fused: msg-GEMM -> c(LDS) -> GRU-GEMM (swapped: features x nodes) -> gates -> out ----
// Block: 512 threads (8 waves), 128 nodes.
// LDS: [0,16K) node-tile [128][64]; [16K,80K) W-tile [512][64]; [80K,112K) c-tile [128][128];
//      out-tile f32 [128][132] overlays at 16K (after GEMMs done).
__global__ __launch_bounds__(512, 2) void fused_kernel(
    const unsigned short* xh, const unsigned short* Sb,
    const unsigned short* Wmsg, const unsigned short* Wbig,
    const float* b_msg, const float* biasb, const int* deg,
    const float* hfull, float* outp, int NN){
  __shared__ __align__(16) char lds[114688];
  char* ldsN = lds;                 // 16KB  [128 nodes][64 k]
  char* ldsW = lds + 16*1024;       // 64KB  [512 feat][64 k]
  char* ldsC = lds + 80*1024;       // 32KB  [128 nodes][128 cc]
  float* ldsO = (float*)(lds + 16*1024); // [128][132] f32

  int tid = threadIdx.x;
  int lane = tid & 63, wv = tid >> 6;
  int l15 = lane & 15, l4 = lane >> 4;
  long nodebase = (long)blockIdx.x * 128;

  // ---------------- phase 1: c = Wmsg (128x256) @ Sb^T (256 x 128nodes) ----------------
  int wm1 = wv >> 2, wn1 = wv & 3;  // 2 x 4: wave-tile 64 feat x 32 nodes
  const f32x4 fz = {0.f,0.f,0.f,0.f};
  f32x4 acc1[4][2];
  #pragma unroll
  for(int m=0;m<4;++m){ acc1[m][0]=fz; acc1[m][1]=fz; }

  for(int kt=0; kt<4; ++kt){
    #pragma unroll
    for(int it=0; it<2; ++it){
      int slot = it*512 + tid;          // 0..1023
      int row = slot >> 3, c = slot & 7;
      int cw = c ^ (row & 7);
      // Wmsg tile [128][64]
      s16x8 vw = *(const s16x8*)(Wmsg + row*256 + kt*64 + c*8);
      *(s16x8*)(ldsW + row*128 + cw*16) = vw;
      // Sb tile [128 nodes][64]
      long gr = nodebase + row; if(gr > NN-1) gr = NN-1;
      s16x8 vn = *(const s16x8*)(Sb + gr*256 + kt*64 + c*8);
      *(s16x8*)(ldsN + row*128 + cw*16) = vn;
    }
    __syncthreads();
    #pragma unroll
    for(int kk=0; kk<2; ++kk){
      s16x8 af[4], bf2_[2];
      #pragma unroll
      for(int m=0;m<4;++m){
        int fr = wm1*64 + m*16 + l15;
        af[m] = *(const s16x8*)(ldsW + fr*128 + (((kk*4+l4) ^ (fr&7))*16));
      }
      #pragma unroll
      for(int n=0;n<2;++n){
        int nr = wn1*32 + n*16 + l15;
        bf2_[n] = *(const s16x8*)(ldsN + nr*128 + (((kk*4+l4) ^ (nr&7))*16));
      }
      #pragma unroll
      for(int m=0;m<4;++m)
        #pragma unroll
        for(int n=0;n<2;++n)
          acc1[m][n] = __builtin_amdgcn_mfma_f32_16x16x32_bf16(af[m], bf2_[n], acc1[m][n], 0, 0, 0);
    }
    __syncthreads();
  }

  // phase 2: bias + deg-mask, bf16, write c-tile to LDS (swizzled like a node-row tile)
  #pragma unroll
  for(int n=0;n<2;++n){
    int node_l = wn1*32 + n*16 + l15;
    long gn = nodebase + node_l; if(gn > NN-1) gn = NN-1;
    int dg = deg[gn];
    float msk = (dg > 0) ? 1.f : 0.f;
    #pragma unroll
    for(int m=0;m<4;++m){
      int ccb = wm1*64 + m*16 + l4*4;
      float4 bm = *(const float4*)(b_msg + ccb);
      ushort4 o;
      o.x = f2bf((acc1[m][n][0] + bm.x)*msk);
      o.y = f2bf((acc1[m][n][1] + bm.y)*msk);
      o.z = f2bf((acc1[m][n][2] + bm.z)*msk);
      o.w = f2bf((acc1[m][n][3] + bm.w)*msk);
      *(ushort4*)(ldsC + node_l*256 + (((ccb>>3) ^ (node_l&7))*16) + (ccb&4)*2) = o;
    }
  }
  __syncthreads();

  // ---------------- phase 3: P^T = Wbig' (512x384) @ [x|c|h]^T ----------------
  int wm = wv >> 1, wn = wv & 1;    // 4 x 2: wave-tile 128 feat x 64 nodes
  f32x4 acc3[8][4];
  #pragma unroll
  for(int m=0;m<8;++m)
    #pragma unroll
    for(int n=0;n<4;++n) acc3[m][n] = fz;

  for(int kt=0; kt<6; ++kt){
    bool useC = (kt >= 2 && kt < 4);
    #pragma unroll
    for(int it=0; it<8; ++it){
      int slot = it*512 + tid;          // 0..4095
      int row = slot >> 3, c = slot & 7;
      int cw = c ^ (row & 7);
      s16x8 vw = *(const s16x8*)(Wbig + (long)row*384 + kt*64 + c*8);
      *(s16x8*)(ldsW + row*128 + cw*16) = vw;
    }
    if(!useC){
      int koff = (kt < 2) ? kt*64 : 128 + (kt-4)*64;
      #pragma unroll
      for(int it=0; it<2; ++it){
        int slot = it*512 + tid;
        int row = slot >> 3, c = slot & 7;
        int cw = c ^ (row & 7);
        long gr = nodebase + row; if(gr > NN-1) gr = NN-1;
        s16x8 vn = *(const s16x8*)(xh + gr*256 + koff + c*8);
        *(s16x8*)(ldsN + row*128 + cw*16) = vn;
      }
    }
    __syncthreads();
    #pragma unroll
    for(int kk=0; kk<2; ++kk){
      s16x8 af[8];
      #pragma unroll
      for(int m=0;m<8;++m){
        int fr = wm*128 + m*16 + l15;
        af[m] = *(const s16x8*)(ldsW + fr*128 + (((kk*4+l4) ^ (fr&7))*16));
      }
      s16x8 bf4[4];
      #pragma unroll
      for(int n=0;n<4;++n){
        int nr = wn*64 + n*16 + l15;
        const char* bp;
        if(useC) bp = ldsC + nr*256 + ((((kt-2)*8 + kk*4 + l4) ^ (nr&7))*16);
        else     bp = ldsN + nr*128 + (((kk*4+l4) ^ (nr&7))*16);
        bf4[n] = *(const s16x8*)bp;
      }
      #pragma unroll
      for(int m=0;m<8;++m)
        #pragma unroll
        for(int n=0;n<4;++n)
          acc3[m][n] = __builtin_amdgcn_mfma_f32_16x16x32_bf16(af[m], bf4[n], acc3[m][n], 0, 0, 0);
    }
    __syncthreads();
  }

  // ---------------- gates epilogue: regs 0..3 of acc3[m][n] = {r,z,sn,hn} of q ----------------
  #pragma unroll
  for(int m=0;m<8;++m){
    int q = wm*32 + m*4 + l4;
    float4 bb = *(const float4*)(biasb + q*4);
    #pragma unroll
    for(int n=0;n<4;++n){
      int node_l = wn*64 + n*16 + l15;
      long gn = nodebase + node_l; if(gn > NN-1) gn = NN-1;
      float hv = hfull[gn*128 + q];
      float vr  = acc3[m][n][0] + bb.x;
      float vz  = acc3[m][n][1] + bb.y;
      float vsn = acc3[m][n][2] + bb.z;
      float vhn = acc3[m][n][3] + bb.w;
      float r = 1.f/(1.f + __expf(-vr));
      float z = 1.f/(1.f + __expf(-vz));
      float narg = vsn + (r - 1.f)*vhn;
      float nn = 2.f/(1.f + __expf(-2.f*narg)) - 1.f;
      ldsO[node_l*132 + q] = (1.f - z)*nn + z*hv;
    }
  }
  __syncthreads();

  // coalesced writeout
  #pragma unroll
  for(int it=0; it<8; ++it){
    int slot = it*512 + tid;            // 0..4095
    int node_l = slot >> 5, c4 = slot & 31;
    long gn = nodebase + node_l;
    if(gn < NN){
      float4 v = *(const float4*)(ldsO + node_l*132 + c4*4);
      *(float4*)(outp + gn*128 + c4*4) = v;
    }
  }
}

extern "C" void kernel_launch(void* const* d_in, const int* in_sizes, int n_in,
                              void* d_out, int out_size, void* d_ws, size_t ws_size,
                              hipStream_t stream){
  const float* x     = (const float*)d_in[0];
  const float* h     = (const float*)d_in[1];
  const int*   src   = (const int*)d_in[2];
  const int*   dst   = (const int*)d_in[3];
  const float* W_msg = (const float*)d_in[4];
  const float* b_msg = (const float*)d_in[5];
  const float* W_ih  = (const float*)d_in[6];
  const float* W_hh  = (const float*)d_in[7];
  const float* b_ih  = (const float*)d_in[8];
  const float* b_hh  = (const float*)d_in[9];
  const int N = in_sizes[0] / H;
  const int E = in_sizes[2];
  float* out = (float*)d_out;

  char* p = (char*)d_ws;
  auto alloc = [&](size_t bytes)->char*{
    char* r = p; p += (bytes + 255) & ~(size_t)255; return r;
  };
  unsigned short* xh    = (unsigned short*)alloc((size_t)N*256*2);
  unsigned short* Sb    = (unsigned short*)alloc((size_t)N*256*2);
  unsigned short* Wmsgb = (unsigned short*)alloc(128*256*2);
  unsigned short* Wbig  = (unsigned short*)alloc(512*384*2);
  float*          biasb = (float*)alloc(512*4);
  int*            deg   = (int*)alloc((size_t)N*4);
  int*            rs    = (int*)alloc((size_t)(N+1)*4);
  int*            rc    = (int*)alloc((size_t)N*4);
  int*            ss    = (int*)alloc((size_t)E*4);
  int*            bsum  = (int*)alloc(64*4);

  hipMemsetAsync(deg, 0, (size_t)N*4, stream);
  prep_kernel<<<(512*384 + 128*256 + 512 + 255)/256, 256, 0, stream>>>(
      W_msg, W_ih, W_hh, b_ih, b_hh, Wmsgb, Wbig, biasb);
  int nv = N*H/4;
  convert_kernel<<<(2*nv + 255)/256, 256, 0, stream>>>(x, h, xh, nv);
  hist_kernel<<<(E + 255)/256, 256, 0, stream>>>(dst, deg, E);
  int nb = (N + 2047)/2048;
  scanA_kernel<<<nb, 256, 0, stream>>>(deg, rs, bsum, N);
  scanB_kernel<<<1, 64, 0, stream>>>(bsum, rs + N, nb);
  scanC_kernel<<<(N + 255)/256, 256, 0, stream>>>(rs, rc, bsum, N);
  fill_kernel<<<(E + 255)/256, 256, 0, stream>>>(src, dst, rc, ss, E);
  agg_kernel<<<(N + 3)/4, 256, 0, stream>>>(xh, rs, ss, Sb, N);

  int nblk = (N + 127)/128;
  fused_kernel<<<nblk, 512, 0, stream>>>(
      xh, Sb, Wmsgb, Wbig, b_msg, biasb, deg, h, out, N);
}

// Round 5
// 243.441 us; speedup vs baseline: 1.0558x; 1.0558x over previous
//
#include <hip/hip_runtime.h>

#define H 128

typedef __attribute__((ext_vector_type(8))) short s16x8;
typedef __attribute__((ext_vector_type(4))) float f32x4;

__device__ __forceinline__ float bf2f(unsigned short u){
  unsigned x = ((unsigned)u) << 16;
  return __builtin_bit_cast(float, x);
}
__device__ __forceinline__ unsigned short f2bf(float f){
  unsigned u = __builtin_bit_cast(unsigned, f);
  u += 0x7fff + ((u >> 16) & 1);
  return (unsigned short)(u >> 16);
}

typedef __attribute__((address_space(1))) void gvoid;
typedef __attribute__((address_space(3))) void lvoid;
__device__ __forceinline__ void gload16(const void* g, void* l){
  __builtin_amdgcn_global_load_lds((gvoid*)(void*)g, (lvoid*)l, 16, 0, 0);
}

// ---- weight prep ----
// WbigT: pre-swizzled LDS-tile order. Logical W'[r'][k], r'=q*4+g (g=0:r 1:z 2:i_n+h_n 3:h_n),
// k = [x(0:128)|c(128:256)|h(256:384)], g=3 zero for k<256.
// Tile layout: i = hf*98304 + kt*16384 + row*64 + cw*8 + j ; content W'[hf*256+row][kt*64 + (cw^(row&7))*8 + j].
// WmsgT: i = kt*8192 + row*64 + cw*8 + j ; content W_msg[row][kt*64 + (cw^(row&7))*8 + j].
__global__ void prep_kernel(const float* W_msg, const float* W_ih, const float* W_hh,
                            const float* b_ih, const float* b_hh,
                            unsigned short* WmsgT, unsigned short* WbigT, float* biasb){
  int i = blockIdx.x*256 + threadIdx.x;
  const int NW = 512*384;
  if(i < NW){
    int hf = i / 98304; int r1 = i % 98304;
    int kt = r1 / 16384; int r2 = r1 % 16384;
    int row = r2 / 64;   int r3 = r2 % 64;
    int cw = r3 >> 3;    int j = r3 & 7;
    int c = cw ^ (row & 7);
    int k = kt*64 + c*8 + j;
    int rp = hf*256 + row;
    int q = rp >> 2, g = rp & 3;
    float v;
    if(g < 3){
      int orow = g*128 + q;
      v = (k < 256) ? W_ih[orow*256 + k] : W_hh[orow*128 + (k-256)];
    } else {
      v = (k < 256) ? 0.f : W_hh[(256 + q)*128 + (k-256)];
    }
    WbigT[i] = f2bf(v);
  } else if(i < NW + 128*256){
    int j2 = i - NW;
    int kt = j2 / 8192; int r2 = j2 % 8192;
    int row = r2 / 64;  int r3 = r2 % 64;
    int cw = r3 >> 3;   int j = r3 & 7;
    int c = cw ^ (row & 7);
    int k = kt*64 + c*8 + j;
    WmsgT[j2] = f2bf(W_msg[row*256 + k]);
  } else if(i < NW + 128*256 + 512){
    int r = i - NW - 128*256;
    int q = r >> 2, g = r & 3;
    biasb[r] = (g < 3) ? (b_ih[g*128+q] + b_hh[g*128+q]) : b_hh[256+q];
  }
}

// ---- convert x,h f32 -> bf16 interleaved xh[N][256] ----
__global__ void convert_kernel(const float* x, const float* h,
                               unsigned short* xh, int nv){
  int i = blockIdx.x*256 + threadIdx.x;
  const float* sp; int j, add;
  if(i < nv){ sp = x; j = i; add = 0; }
  else if(i < 2*nv){ sp = h; j = i - nv; add = 128; }
  else return;
  float4 v = ((const float4*)sp)[j];
  ushort4 o; o.x=f2bf(v.x); o.y=f2bf(v.y); o.z=f2bf(v.z); o.w=f2bf(v.w);
  int node = j >> 5, col = (j & 31)*4;
  *(ushort4*)(xh + (long)node*256 + add + col) = o;
}

// ---- CSR build ----
__global__ void hist_kernel(const int* dst, int* deg, int E){
  int e = blockIdx.x*256 + threadIdx.x;
  if(e < E) atomicAdd(&deg[dst[e]], 1);
}

__global__ void scanA_kernel(const int* deg, int* rs, int* bsum, int N){
  __shared__ int buf[256];
  int b = blockIdx.x, t = threadIdx.x;
  int base = b*2048 + t*8;
  int v[8]; int s = 0;
  #pragma unroll
  for(int j=0;j<8;++j){ int idx = base+j; v[j] = (idx<N)?deg[idx]:0; s += v[j]; }
  buf[t] = s; __syncthreads();
  #pragma unroll
  for(int off=1; off<256; off<<=1){
    int u = (t>=off)?buf[t-off]:0;
    __syncthreads();
    buf[t] += u;
    __syncthreads();
  }
  int run = buf[t] - s;
  #pragma unroll
  for(int j=0;j<8;++j){ int idx = base+j; if(idx<N) rs[idx] = run; run += v[j]; }
  if(t == 255) bsum[b] = buf[255];
}

__global__ void scanB_kernel(int* bsum, int* rsN, int nb){
  __shared__ int buf[64];
  int t = threadIdx.x;
  int v = (t < nb) ? bsum[t] : 0;
  buf[t] = v; __syncthreads();
  #pragma unroll
  for(int off=1; off<64; off<<=1){
    int u = (t>=off)?buf[t-off]:0;
    __syncthreads();
    buf[t] += u;
    __syncthreads();
  }
  if(t < nb) bsum[t] = buf[t] - v;
  if(t == 63) *rsN = buf[63];
}

__global__ void scanC_kernel(int* rs, int* rc, const int* bsum, int N){
  int i = blockIdx.x*256 + threadIdx.x;
  if(i < N){ int v = rs[i] + bsum[i >> 11]; rs[i] = v; rc[i] = v; }
}

__global__ void fill_kernel(const int* src, const int* dst, int* rc, int* ss, int E){
  int e = blockIdx.x*256 + threadIdx.x;
  if(e < E){ int p = atomicAdd(&rc[dst[e]], 1); ss[p] = src[e]; }
}

// ---- aggregation: one wave per node; 2 edges/iter (half-wave each, 16B/lane), unroll x2 ----
__global__ void agg_kernel(const unsigned short* xh, const int* rs, const int* ss,
                           unsigned short* Sb, int N){
  int wv = threadIdx.x >> 6, lane = threadIdx.x & 63;
  int node = blockIdx.x*4 + wv;
  if(node >= N) return;
  int e0 = rs[node], e1 = rs[node+1];
  int half = lane >> 5;
  int co = (lane & 31)*8;
  float a[8] = {0.f,0.f,0.f,0.f,0.f,0.f,0.f,0.f};
  int cnt = e1 - e0;
  int pairs = cnt >> 1;
  int i = 0;
  for(; i+1 < pairs; i += 2){
    int ea = e0 + 2*i + half;
    int eb = ea + 2;
    int sa = ss[ea], sb = ss[eb];
    s16x8 va = *(const s16x8*)(xh + (long)sa*256 + co);
    s16x8 vb = *(const s16x8*)(xh + (long)sb*256 + co);
    #pragma unroll
    for(int j=0;j<8;++j) a[j] += bf2f((unsigned short)va[j]);
    #pragma unroll
    for(int j=0;j<8;++j) a[j] += bf2f((unsigned short)vb[j]);
  }
  for(; i < pairs; ++i){
    int ea = e0 + 2*i + half;
    int sa = ss[ea];
    s16x8 va = *(const s16x8*)(xh + (long)sa*256 + co);
    #pragma unroll
    for(int j=0;j<8;++j) a[j] += bf2f((unsigned short)va[j]);
  }
  if((cnt & 1) && half == 0){
    int sa = ss[e1-1];
    s16x8 va = *(const s16x8*)(xh + (long)sa*256 + co);
    #pragma unroll
    for(int j=0;j<8;++j) a[j] += bf2f((unsigned short)va[j]);
  }
  #pragma unroll
  for(int j=0;j<8;++j) a[j] += __shfl_xor(a[j], 32, 64);
  if(half == 0){
    float inv = (cnt > 0) ? 1.0f/(float)cnt : 0.f;
    unsigned short o[8];
    #pragma unroll
    for(int j=0;j<8;++j) o[j] = f2bf(a[j]*inv);
    *(s16x8*)(Sb + (long)node*256 + co) = *(const s16x8*)o;
  }
}

// ---- fused: msg-GEMM -> c(LDS) -> GRU-GEMM (2 output halves) -> gates -> out ----
// 512 threads (8 waves), 128 nodes/block. LDS 80KB -> 2 blocks/CU.
// ldsW [256][128B] 32K | ldsN [128][128B] 16K | ldsC [128][256B] 32K ; ldsO overlays W+N.
__global__ __launch_bounds__(512, 4) void fused_kernel(
    const unsigned short* xh, const unsigned short* Sb,
    const unsigned short* WmsgT, const unsigned short* WbigT,
    const float* b_msg, const float* biasb, const int* deg,
    const float* hfull, float* outp, int NN){
  __shared__ __align__(16) char lds[81920];
  char* ldsW = lds;
  char* ldsN = lds + 32*1024;
  char* ldsC = lds + 48*1024;
  float* ldsO = (float*)lds;   // [128][68] f32, overlays W+N after GEMM of each half

  int tid = threadIdx.x;
  int lane = tid & 63, wv = tid >> 6;
  int l15 = lane & 15, l4 = lane >> 4;
  long nodebase = (long)blockIdx.x * 128;
  const f32x4 fz = {0.f,0.f,0.f,0.f};

  // ---------------- phase 1: c = Wmsg (128x256) @ Sb^T ----------------
  int wm1 = wv >> 2, wn1 = wv & 3;  // 2 x 4: wave-tile 64 feat x 32 nodes
  f32x4 acc1[4][2];
  #pragma unroll
  for(int m=0;m<4;++m){ acc1[m][0]=fz; acc1[m][1]=fz; }

  for(int kt=0; kt<4; ++kt){
    #pragma unroll
    for(int it=0; it<2; ++it){
      int slot = it*512 + tid;
      // W tile (pre-swizzled, linear DMA)
      gload16(WmsgT + kt*8192 + slot*8, ldsW + it*8192 + wv*1024);
      // node tile: inverse-swizzled global source, linear LDS dest
      int row = slot >> 3, cw = slot & 7;
      int c = cw ^ (row & 7);
      long gr = nodebase + row; if(gr > NN-1) gr = NN-1;
      gload16(Sb + gr*256 + kt*64 + c*8, ldsN + it*8192 + wv*1024);
    }
    __syncthreads();
    #pragma unroll
    for(int kk=0; kk<2; ++kk){
      s16x8 af[4], bf2_[2];
      #pragma unroll
      for(int m=0;m<4;++m){
        int fr = wm1*64 + m*16 + l15;
        af[m] = *(const s16x8*)(ldsW + fr*128 + (((kk*4+l4) ^ (fr&7))*16));
      }
      #pragma unroll
      for(int n=0;n<2;++n){
        int nr = wn1*32 + n*16 + l15;
        bf2_[n] = *(const s16x8*)(ldsN + nr*128 + (((kk*4+l4) ^ (nr&7))*16));
      }
      #pragma unroll
      for(int m=0;m<4;++m)
        #pragma unroll
        for(int n=0;n<2;++n)
          acc1[m][n] = __builtin_amdgcn_mfma_f32_16x16x32_bf16(af[m], bf2_[n], acc1[m][n], 0, 0, 0);
    }
    __syncthreads();
  }

  // phase 2: bias + deg-mask, bf16, write c-tile to LDS (swizzled)
  #pragma unroll
  for(int n=0;n<2;++n){
    int node_l = wn1*32 + n*16 + l15;
    long gn = nodebase + node_l; if(gn > NN-1) gn = NN-1;
    int dg = deg[gn];
    float msk = (dg > 0) ? 1.f : 0.f;
    #pragma unroll
    for(int m=0;m<4;++m){
      int ccb = wm1*64 + m*16 + l4*4;
      float4 bm = *(const float4*)(b_msg + ccb);
      ushort4 o;
      o.x = f2bf((acc1[m][n][0] + bm.x)*msk);
      o.y = f2bf((acc1[m][n][1] + bm.y)*msk);
      o.z = f2bf((acc1[m][n][2] + bm.z)*msk);
      o.w = f2bf((acc1[m][n][3] + bm.w)*msk);
      *(ushort4*)(ldsC + node_l*256 + (((ccb>>3) ^ (node_l&7))*16) + (ccb&4)*2) = o;
    }
  }
  __syncthreads();

  // ---------------- phase 3: two output halves of P' = Wbig' @ [x|c|h]^T ----------------
  int wm = wv >> 1, wn = wv & 1;    // 4 x 2: wave-tile 64 feat x 64 nodes (per half)
  for(int hf=0; hf<2; ++hf){
    f32x4 acc3[4][4];
    #pragma unroll
    for(int m=0;m<4;++m)
      #pragma unroll
      for(int n=0;n<4;++n) acc3[m][n] = fz;

    for(int kt=0; kt<6; ++kt){
      bool useC = (kt >= 2 && kt < 4);
      long wbase = ((long)hf*6 + kt)*16384;   // shorts per [256][64] tile
      #pragma unroll
      for(int it=0; it<4; ++it){
        int slot = it*512 + tid;
        gload16(WbigT + wbase + slot*8, ldsW + it*8192 + wv*1024);
      }
      if(!useC){
        int koff = (kt < 2) ? kt*64 : 128 + (kt-4)*64;
        #pragma unroll
        for(int it=0; it<2; ++it){
          int slot = it*512 + tid;
          int row = slot >> 3, cw = slot & 7;
          int c = cw ^ (row & 7);
          long gr = nodebase + row; if(gr > NN-1) gr = NN-1;
          gload16(xh + gr*256 + koff + c*8, ldsN + it*8192 + wv*1024);
        }
      }
      __syncthreads();
      #pragma unroll
      for(int kk=0; kk<2; ++kk){
        s16x8 af[4];
        #pragma unroll
        for(int m=0;m<4;++m){
          int fr = wm*64 + m*16 + l15;
          af[m] = *(const s16x8*)(ldsW + fr*128 + (((kk*4+l4) ^ (fr&7))*16));
        }
        s16x8 bf4[4];
        #pragma unroll
        for(int n=0;n<4;++n){
          int nr = wn*64 + n*16 + l15;
          const char* bp;
          if(useC) bp = ldsC + nr*256 + ((((kt-2)*8 + kk*4 + l4) ^ (nr&7))*16);
          else     bp = ldsN + nr*128 + (((kk*4+l4) ^ (nr&7))*16);
          bf4[n] = *(const s16x8*)bp;
        }
        #pragma unroll
        for(int m=0;m<4;++m)
          #pragma unroll
          for(int n=0;n<4;++n)
            acc3[m][n] = __builtin_amdgcn_mfma_f32_16x16x32_bf16(af[m], bf4[n], acc3[m][n], 0, 0, 0);
      }
      __syncthreads();
    }

    // gates epilogue for this half: lane regs 0..3 = {r,z,sn,hn} of q = hf*64 + wm*16 + m*4 + l4
    #pragma unroll
    for(int m=0;m<4;++m){
      int q = hf*64 + wm*16 + m*4 + l4;
      int ql = q & 63;
      float4 bb = *(const float4*)(biasb + q*4);
      #pragma unroll
      for(int n=0;n<4;++n){
        int node_l = wn*64 + n*16 + l15;
        long gn = nodebase + node_l; if(gn > NN-1) gn = NN-1;
        float hv = hfull[gn*128 + q];
        float vr  = acc3[m][n][0] + bb.x;
        float vz  = acc3[m][n][1] + bb.y;
        float vsn = acc3[m][n][2] + bb.z;
        float vhn = acc3[m][n][3] + bb.w;
        float r = 1.f/(1.f + __expf(-vr));
        float z = 1.f/(1.f + __expf(-vz));
        float narg = vsn + (r - 1.f)*vhn;
        float nn2 = 2.f/(1.f + __expf(-2.f*narg)) - 1.f;
        ldsO[node_l*68 + ql] = (1.f - z)*nn2 + z*hv;
      }
    }
    __syncthreads();

    // coalesced writeout of this 64-col half
    #pragma unroll
    for(int it=0; it<4; ++it){
      int slot = it*512 + tid;            // 0..2047 = 128 nodes x 16 float4
      int node_l = slot >> 4, f4 = slot & 15;
      long gn = nodebase + node_l;
      if(gn < NN){
        float4 v = *(const float4*)(ldsO + node_l*68 + f4*4);
        *(float4*)(outp + gn*128 + hf*64 + f4*4) = v;
      }
    }
    __syncthreads();
  }
}

extern "C" void kernel_launch(void* const* d_in, const int* in_sizes, int n_in,
                              void* d_out, int out_size, void* d_ws, size_t ws_size,
                              hipStream_t stream){
  const float* x     = (const float*)d_in[0];
  const float* h     = (const float*)d_in[1];
  const int*   src   = (const int*)d_in[2];
  const int*   dst   = (const int*)d_in[3];
  const float* W_msg = (const float*)d_in[4];
  const float* b_msg = (const float*)d_in[5];
  const float* W_ih  = (const float*)d_in[6];
  const float* W_hh  = (const float*)d_in[7];
  const float* b_ih  = (const float*)d_in[8];
  const float* b_hh  = (const float*)d_in[9];
  const int N = in_sizes[0] / H;
  const int E = in_sizes[2];
  float* out = (float*)d_out;

  char* p = (char*)d_ws;
  auto alloc = [&](size_t bytes)->char*{
    char* r = p; p += (bytes + 255) & ~(size_t)255; return r;
  };
  unsigned short* xh    = (unsigned short*)alloc((size_t)N*256*2);
  unsigned short* Sb    = (unsigned short*)alloc((size_t)N*256*2);
  unsigned short* WmsgT = (unsigned short*)alloc(128*256*2);
  unsigned short* WbigT = (unsigned short*)alloc(512*384*2);
  float*          biasb = (float*)alloc(512*4);
  int*            deg   = (int*)alloc((size_t)N*4);
  int*            rs    = (int*)alloc((size_t)(N+1)*4);
  int*            rc    = (int*)alloc((size_t)N*4);
  int*            ss    = (int*)alloc((size_t)E*4);
  int*            bsum  = (int*)alloc(64*4);

  hipMemsetAsync(deg, 0, (size_t)N*4, stream);
  prep_kernel<<<(512*384 + 128*256 + 512 + 255)/256, 256, 0, stream>>>(
      W_msg, W_ih, W_hh, b_ih, b_hh, WmsgT, WbigT, biasb);
  int nv = N*H/4;
  convert_kernel<<<(2*nv + 255)/256, 256, 0, stream>>>(x, h, xh, nv);
  hist_kernel<<<(E + 255)/256, 256, 0, stream>>>(dst, deg, E);
  int nb = (N + 2047)/2048;
  scanA_kernel<<<nb, 256, 0, stream>>>(deg, rs, bsum, N);
  scanB_kernel<<<1, 64, 0, stream>>>(bsum, rs + N, nb);
  scanC_kernel<<<(N + 255)/256, 256, 0, stream>>>(rs, rc, bsum, N);
  fill_kernel<<<(E + 255)/256, 256, 0, stream>>>(src, dst, rc, ss, E);
  agg_kernel<<<(N + 3)/4, 256, 0, stream>>>(xh, rs, ss, Sb, N);

  int nblk = (N + 127)/128;
  fused_kernel<<<nblk, 512, 0, stream>>>(
      xh, Sb, WmsgT, WbigT, b_msg, biasb, deg, h, out, N);
}